// Round 1
// baseline (360.290 us; speedup 1.0000x reference)
//
#include <hip/hip_runtime.h>
#include <hip/hip_bf16.h>

// GCN: h1 = relu(GCNConv(x, W1, b1)); h2 = relu(GCNConv(h1, W2, b2));
// pooled = segment_sum(h2, batch); out = log_softmax(pooled @ Wh + bh)
// GCNConv(x,W,b): h = x@W; out = sum_{e:dst=i} dinv[src]*dinv[i]*h[src] + dinv[i]^2*h[i] + b
// deg[i] = 1 + #edges with dst==i; dinv = rsqrt(deg)

#define DIM 128
#define NCLS 64

// ---------------- CSR build ----------------

__global__ void count_dst(const int* __restrict__ dst, int* __restrict__ cnt, int E) {
    int e = blockIdx.x * 256 + threadIdx.x;
    if (e < E) atomicAdd(&cnt[dst[e]], 1);
}

// per-1024 chunk exclusive scan (partial) + block sums + dinv
__global__ __launch_bounds__(1024) void scan_block(const int* __restrict__ cnt,
                                                   int* __restrict__ partial,
                                                   int* __restrict__ bsum,
                                                   float* __restrict__ dinv, int n) {
    __shared__ int wsum[16];
    int gid = blockIdx.x * 1024 + threadIdx.x;
    int v = (gid < n) ? cnt[gid] : 0;
    if (gid < n) dinv[gid] = rsqrtf(1.0f + (float)v);
    int lane = threadIdx.x & 63;
    int wave = threadIdx.x >> 6;
    int s = v;
    #pragma unroll
    for (int d = 1; d < 64; d <<= 1) {
        int t = __shfl_up(s, d, 64);
        if (lane >= d) s += t;
    }
    if (lane == 63) wsum[wave] = s;
    __syncthreads();
    if (threadIdx.x < 16) {
        int t = wsum[threadIdx.x];
        #pragma unroll
        for (int d = 1; d < 16; d <<= 1) {
            int u = __shfl_up(t, d, 64);
            if ((int)threadIdx.x >= d) t += u;
        }
        wsum[threadIdx.x] = t;  // inclusive over waves
    }
    __syncthreads();
    int woff = (wave == 0) ? 0 : wsum[wave - 1];
    if (gid < n) partial[gid] = woff + s - v;  // exclusive within chunk
    if (threadIdx.x == 0) bsum[blockIdx.x] = wsum[15];
}

__global__ void scan_small(int* __restrict__ bsum, int nb) {
    int l = threadIdx.x;
    int v = (l < nb) ? bsum[l] : 0;
    int s = v;
    #pragma unroll
    for (int d = 1; d < 64; d <<= 1) {
        int t = __shfl_up(s, d, 64);
        if (l >= d) s += t;
    }
    if (l < nb) bsum[l] = s - v;  // exclusive
}

__global__ void finalize_rowoff(const int* __restrict__ partial, const int* __restrict__ bsum,
                                int* __restrict__ row_off, int n, int E) {
    int i = blockIdx.x * 256 + threadIdx.x;
    if (i < n) row_off[i] = partial[i] + bsum[i >> 10];
    if (i == 0) row_off[n] = E;
}

__global__ void scatter_csr(const int* __restrict__ src, const int* __restrict__ dst,
                            const int* __restrict__ row_off, int* __restrict__ cursor,
                            int* __restrict__ csr_src, int E) {
    int e = blockIdx.x * 256 + threadIdx.x;
    if (e >= E) return;
    int d = dst[e];
    int pos = atomicAdd(&cursor[d], 1);
    csr_src[row_off[d] + pos] = src[e];
}

// ---------------- dense GEMM: C[N][128] = A[N][128] @ W[128][128] ----------------

#define GTM 64
#define GTK 32

__global__ __launch_bounds__(256) void gemm_xw(const float* __restrict__ A,
                                               const float* __restrict__ W,
                                               float* __restrict__ C, int N) {
    __shared__ float As[GTK][GTM + 1];   // [k][r], +1 pad
    __shared__ float Ws[GTK][DIM];       // [k][c]
    const int tid = threadIdx.x;
    const int row0 = blockIdx.x * GTM;
    const int cg = tid & 15;   // cols cg*8 .. cg*8+7
    const int rg = tid >> 4;   // rows rg*4 .. rg*4+3
    float acc[4][8];
    #pragma unroll
    for (int i = 0; i < 4; ++i)
        #pragma unroll
        for (int j = 0; j < 8; ++j) acc[i][j] = 0.f;

    const int ka = tid & 31;   // A-load k
    const int ra = tid >> 5;   // A-load row base (0..7)
    const int cw = tid & 127;  // W-load col
    const int kw0 = tid >> 7;  // W-load k base (0..1)

    for (int kk = 0; kk < DIM; kk += GTK) {
        #pragma unroll
        for (int rr = 0; rr < GTM; rr += 8) {
            int row = row0 + ra + rr;
            As[ka][ra + rr] = (row < N) ? A[row * DIM + kk + ka] : 0.f;
        }
        #pragma unroll
        for (int k = 0; k < GTK; k += 2) {
            Ws[kw0 + k][cw] = W[(kk + kw0 + k) * DIM + cw];
        }
        __syncthreads();
        #pragma unroll
        for (int k = 0; k < GTK; ++k) {
            float a[4], w[8];
            #pragma unroll
            for (int i = 0; i < 4; ++i) a[i] = As[k][rg * 4 + i];
            #pragma unroll
            for (int j = 0; j < 8; ++j) w[j] = Ws[k][cg * 8 + j];
            #pragma unroll
            for (int i = 0; i < 4; ++i)
                #pragma unroll
                for (int j = 0; j < 8; ++j) acc[i][j] = fmaf(a[i], w[j], acc[i][j]);
        }
        __syncthreads();
    }
    #pragma unroll
    for (int i = 0; i < 4; ++i) {
        int row = row0 + rg * 4 + i;
        if (row < N) {
            #pragma unroll
            for (int j = 0; j < 8; ++j) C[row * DIM + cg * 8 + j] = acc[i][j];
        }
    }
}

// ---------------- neighbor aggregation + self loop + bias + relu ----------------
// out[i][c] = relu(b[c] + dinv[i]^2*h[i][c] + sum_e dinv[i]*dinv[s]*h[s][c])

__global__ __launch_bounds__(128) void aggregate(const float* __restrict__ h,
                                                 const float* __restrict__ dinv,
                                                 const int* __restrict__ row_off,
                                                 const int* __restrict__ csr_src,
                                                 const float* __restrict__ bias,
                                                 float* __restrict__ out, int n) {
    int i = blockIdx.x;
    int c = threadIdx.x;
    float di = dinv[i];
    float acc = bias[c] + di * di * h[(long)i * DIM + c];
    int e0 = row_off[i], e1 = row_off[i + 1];
    int e = e0;
    for (; e + 4 <= e1; e += 4) {
        int s0 = csr_src[e], s1 = csr_src[e + 1], s2 = csr_src[e + 2], s3 = csr_src[e + 3];
        float d0 = dinv[s0], d1 = dinv[s1], d2 = dinv[s2], d3 = dinv[s3];
        float v0 = h[(long)s0 * DIM + c];
        float v1 = h[(long)s1 * DIM + c];
        float v2 = h[(long)s2 * DIM + c];
        float v3 = h[(long)s3 * DIM + c];
        acc = fmaf(di * d0, v0, acc);
        acc = fmaf(di * d1, v1, acc);
        acc = fmaf(di * d2, v2, acc);
        acc = fmaf(di * d3, v3, acc);
    }
    for (; e < e1; ++e) {
        int s = csr_src[e];
        acc = fmaf(di * dinv[s], h[(long)s * DIM + c], acc);
    }
    out[(long)i * DIM + c] = fmaxf(acc, 0.f);
}

// ---------------- graph segment boundaries (x_batch is sorted) ----------------

__global__ void graph_bounds(const int* __restrict__ batch, int* __restrict__ gstart,
                             int n, int ngraph) {
    int i = blockIdx.x * 256 + threadIdx.x;
    if (i >= n) return;
    int b = batch[i];
    int prev = (i == 0) ? -1 : batch[i - 1];
    for (int g = prev + 1; g <= b; ++g) gstart[g] = i;
    if (i == n - 1) {
        for (int g = b + 1; g <= ngraph; ++g) gstart[g] = n;
    }
}

// ---------------- pool + head GEMM + log_softmax ----------------

__global__ __launch_bounds__(128) void pool_head(const float* __restrict__ h2,
                                                 const int* __restrict__ gstart,
                                                 const float* __restrict__ Wh,
                                                 const float* __restrict__ bh,
                                                 float* __restrict__ out) {
    __shared__ float pl[DIM];
    int g = blockIdx.x;
    int c = threadIdx.x;
    int i0 = gstart[g], i1 = gstart[g + 1];
    float p = 0.f;
    for (int i = i0; i < i1; ++i) p += h2[(long)i * DIM + c];
    pl[c] = p;
    __syncthreads();
    if (threadIdx.x < NCLS) {
        int o = threadIdx.x;
        float logit = bh[o];
        #pragma unroll 8
        for (int cc = 0; cc < DIM; ++cc) logit = fmaf(pl[cc], Wh[cc * NCLS + o], logit);
        float m = logit;
        #pragma unroll
        for (int d = 32; d >= 1; d >>= 1) m = fmaxf(m, __shfl_xor(m, d, 64));
        float ex = __expf(logit - m);
        float ssum = ex;
        #pragma unroll
        for (int d = 32; d >= 1; d >>= 1) ssum += __shfl_xor(ssum, d, 64);
        out[g * NCLS + o] = logit - m - __logf(ssum);
    }
}

// ---------------- launch ----------------

extern "C" void kernel_launch(void* const* d_in, const int* in_sizes, int n_in,
                              void* d_out, int out_size, void* d_ws, size_t ws_size,
                              hipStream_t stream) {
    const float* x  = (const float*)d_in[0];
    const int*   ei = (const int*)d_in[1];
    const int*   xb = (const int*)d_in[2];
    const float* W1 = (const float*)d_in[3];
    const float* b1 = (const float*)d_in[4];
    const float* W2 = (const float*)d_in[5];
    const float* b2 = (const float*)d_in[6];
    const float* Wh = (const float*)d_in[7];
    const float* bh = (const float*)d_in[8];
    float* out = (float*)d_out;

    const int N = in_sizes[0] / DIM;       // 50000
    const int E = in_sizes[1] / 2;         // 640000
    const int G = out_size / NCLS;         // 512
    const int* srcv = ei;
    const int* dstv = ei + E;

    // workspace carve-up
    char* w = (char*)d_ws;
    auto alloc = [&](size_t bytes) {
        char* p = w;
        w += (bytes + 255) & ~(size_t)255;
        return p;
    };
    int*   cnt     = (int*)alloc((size_t)N * 4);
    int*   cursor  = (int*)alloc((size_t)N * 4);
    int*   partial = (int*)alloc((size_t)N * 4);
    int*   bsum    = (int*)alloc(256 * 4);
    int*   row_off = (int*)alloc(((size_t)N + 1) * 4);
    int*   gstart  = (int*)alloc(((size_t)G + 1) * 4);
    int*   csr_src = (int*)alloc((size_t)E * 4);
    float* dinv    = (float*)alloc((size_t)N * 4);
    float* Htmp    = (float*)alloc((size_t)N * DIM * 4);
    float* H1      = (float*)alloc((size_t)N * DIM * 4);

    hipMemsetAsync(cnt, 0, (size_t)N * 4, stream);
    hipMemsetAsync(cursor, 0, (size_t)N * 4, stream);

    const int eb = (E + 255) / 256;
    const int nb1024 = (N + 1023) / 1024;
    const int nb256 = (N + 255) / 256;

    count_dst<<<eb, 256, 0, stream>>>(dstv, cnt, E);
    scan_block<<<nb1024, 1024, 0, stream>>>(cnt, partial, bsum, dinv, N);
    scan_small<<<1, 64, 0, stream>>>(bsum, nb1024);
    finalize_rowoff<<<nb256, 256, 0, stream>>>(partial, bsum, row_off, N, E);
    scatter_csr<<<eb, 256, 0, stream>>>(srcv, dstv, row_off, cursor, csr_src, E);

    const int gb = (N + GTM - 1) / GTM;
    // layer 1
    gemm_xw<<<gb, 256, 0, stream>>>(x, W1, Htmp, N);
    aggregate<<<N, 128, 0, stream>>>(Htmp, dinv, row_off, csr_src, b1, H1, N);
    // layer 2
    gemm_xw<<<gb, 256, 0, stream>>>(H1, W2, Htmp, N);
    aggregate<<<N, 128, 0, stream>>>(Htmp, dinv, row_off, csr_src, b2, H1, N);
    // pool + head
    graph_bounds<<<nb256, 256, 0, stream>>>(xb, gstart, N, G);
    pool_head<<<G, 128, 0, stream>>>(H1, gstart, Wh, bh, out);
}

// Round 2
// 302.003 us; speedup vs baseline: 1.1930x; 1.1930x over previous
//
#include <hip/hip_runtime.h>
#include <hip/hip_bf16.h>

// GCN: h1 = relu(GCNConv(x, W1, b1)); h2 = relu(GCNConv(h1, W2, b2));
// pooled = segment_sum(h2, batch); out = log_softmax(pooled @ Wh + bh)
// Intermediates h stored as bf16 (halves the dominant edge-gather traffic);
// all accumulation, weights, coefficients stay fp32.

#define DIM 128
#define NCLS 64

__device__ inline float b2f(unsigned short u) {
    union { unsigned int i; float f; } v; v.i = ((unsigned int)u) << 16; return v.f;
}
__device__ inline unsigned short f2b(float f) {
    union { float f; unsigned int i; } v; v.f = f;
    unsigned int r = v.i + 0x7FFFu + ((v.i >> 16) & 1u);  // round-to-nearest-even
    return (unsigned short)(r >> 16);
}

// ---------------- CSR build ----------------

__global__ void count_dst(const int* __restrict__ dst, int* __restrict__ cnt, int E) {
    int e = blockIdx.x * 256 + threadIdx.x;
    if (e < E) atomicAdd(&cnt[dst[e]], 1);
}

// per-1024 chunk exclusive scan (partial) + block sums + dinv
__global__ __launch_bounds__(1024) void scan_block(const int* __restrict__ cnt,
                                                   int* __restrict__ partial,
                                                   int* __restrict__ bsum,
                                                   float* __restrict__ dinv, int n) {
    __shared__ int wsum[16];
    int gid = blockIdx.x * 1024 + threadIdx.x;
    int v = (gid < n) ? cnt[gid] : 0;
    if (gid < n) dinv[gid] = rsqrtf(1.0f + (float)v);
    int lane = threadIdx.x & 63;
    int wave = threadIdx.x >> 6;
    int s = v;
    #pragma unroll
    for (int d = 1; d < 64; d <<= 1) {
        int t = __shfl_up(s, d, 64);
        if (lane >= d) s += t;
    }
    if (lane == 63) wsum[wave] = s;
    __syncthreads();
    if (threadIdx.x < 16) {
        int t = wsum[threadIdx.x];
        #pragma unroll
        for (int d = 1; d < 16; d <<= 1) {
            int u = __shfl_up(t, d, 64);
            if ((int)threadIdx.x >= d) t += u;
        }
        wsum[threadIdx.x] = t;  // inclusive over waves
    }
    __syncthreads();
    int woff = (wave == 0) ? 0 : wsum[wave - 1];
    if (gid < n) partial[gid] = woff + s - v;  // exclusive within chunk
    if (threadIdx.x == 0) bsum[blockIdx.x] = wsum[15];
}

__global__ void scan_small(int* __restrict__ bsum, int nb) {
    int l = threadIdx.x;
    int v = (l < nb) ? bsum[l] : 0;
    int s = v;
    #pragma unroll
    for (int d = 1; d < 64; d <<= 1) {
        int t = __shfl_up(s, d, 64);
        if (l >= d) s += t;
    }
    if (l < nb) bsum[l] = s - v;  // exclusive
}

__global__ void finalize_rowoff(const int* __restrict__ partial, const int* __restrict__ bsum,
                                int* __restrict__ row_off, int* __restrict__ cursor,
                                int n, int E) {
    int i = blockIdx.x * 256 + threadIdx.x;
    if (i < n) {
        int r = partial[i] + bsum[i >> 10];
        row_off[i] = r;
        cursor[i] = r;
    }
    if (i == 0) row_off[n] = E;
}

__global__ void scatter_csr(const int* __restrict__ src, const int* __restrict__ dst,
                            int* __restrict__ cursor, int* __restrict__ csr_src, int E) {
    int e = blockIdx.x * 256 + threadIdx.x;
    if (e >= E) return;
    int d = dst[e];
    int pos = atomicAdd(&cursor[d], 1);  // absolute position (cursor init = row_off)
    csr_src[pos] = src[e];
}

// ---------------- dense GEMM: C[N][128](bf16) = A[N][128] @ W[128][128] ----------------

#define GTM 64
#define GTK 32

template <typename T>
__device__ inline float load_elem(const T* p);
template <> __device__ inline float load_elem<float>(const float* p) { return *p; }
template <> __device__ inline float load_elem<unsigned short>(const unsigned short* p) { return b2f(*p); }

template <typename T>
__global__ __launch_bounds__(256) void gemm_xw(const T* __restrict__ A,
                                               const float* __restrict__ W,
                                               unsigned short* __restrict__ C, int N) {
    __shared__ float As[GTK][GTM + 1];   // [k][r], +1 pad
    __shared__ float Ws[GTK][DIM];       // [k][c]
    const int tid = threadIdx.x;
    const int row0 = blockIdx.x * GTM;
    const int cg = tid & 15;   // cols cg*8 .. cg*8+7
    const int rg = tid >> 4;   // rows rg*4 .. rg*4+3
    float acc[4][8];
    #pragma unroll
    for (int i = 0; i < 4; ++i)
        #pragma unroll
        for (int j = 0; j < 8; ++j) acc[i][j] = 0.f;

    const int ka = tid & 31;   // A-load k
    const int ra = tid >> 5;   // A-load row base (0..7)
    const int cw = tid & 127;  // W-load col
    const int kw0 = tid >> 7;  // W-load k base (0..1)

    for (int kk = 0; kk < DIM; kk += GTK) {
        #pragma unroll
        for (int rr = 0; rr < GTM; rr += 8) {
            int row = row0 + ra + rr;
            As[ka][ra + rr] = (row < N) ? load_elem(&A[(long)row * DIM + kk + ka]) : 0.f;
        }
        #pragma unroll
        for (int k = 0; k < GTK; k += 2) {
            Ws[kw0 + k][cw] = W[(kk + kw0 + k) * DIM + cw];
        }
        __syncthreads();
        #pragma unroll
        for (int k = 0; k < GTK; ++k) {
            float a[4], w[8];
            #pragma unroll
            for (int i = 0; i < 4; ++i) a[i] = As[k][rg * 4 + i];
            #pragma unroll
            for (int j = 0; j < 8; ++j) w[j] = Ws[k][cg * 8 + j];
            #pragma unroll
            for (int i = 0; i < 4; ++i)
                #pragma unroll
                for (int j = 0; j < 8; ++j) acc[i][j] = fmaf(a[i], w[j], acc[i][j]);
        }
        __syncthreads();
    }
    #pragma unroll
    for (int i = 0; i < 4; ++i) {
        int row = row0 + rg * 4 + i;
        if (row < N) {
            #pragma unroll
            for (int j = 0; j < 8; ++j)
                C[(long)row * DIM + cg * 8 + j] = f2b(acc[i][j]);
        }
    }
}

// ---------------- neighbor aggregation + self loop + bias + relu (bf16 h) ----------------
// One wave per node; each lane handles a bf16 pair (4 B/lane loads).

__global__ __launch_bounds__(64) void aggregate(const ushort2* __restrict__ h,
                                                const float* __restrict__ dinv,
                                                const int* __restrict__ row_off,
                                                const int* __restrict__ csr_src,
                                                const float* __restrict__ bias,
                                                ushort2* __restrict__ out, int n) {
    int i = blockIdx.x;
    int c2 = threadIdx.x;          // pair index 0..63
    float di = dinv[i];
    ushort2 hv = h[(long)i * 64 + c2];
    float ax = bias[2 * c2]     + di * di * b2f(hv.x);
    float ay = bias[2 * c2 + 1] + di * di * b2f(hv.y);
    int e0 = row_off[i], e1 = row_off[i + 1];
    int e = e0;
    for (; e + 4 <= e1; e += 4) {
        int s0 = csr_src[e], s1 = csr_src[e + 1], s2 = csr_src[e + 2], s3 = csr_src[e + 3];
        float w0 = di * dinv[s0], w1 = di * dinv[s1], w2 = di * dinv[s2], w3 = di * dinv[s3];
        ushort2 v0 = h[(long)s0 * 64 + c2];
        ushort2 v1 = h[(long)s1 * 64 + c2];
        ushort2 v2 = h[(long)s2 * 64 + c2];
        ushort2 v3 = h[(long)s3 * 64 + c2];
        ax = fmaf(w0, b2f(v0.x), ax); ay = fmaf(w0, b2f(v0.y), ay);
        ax = fmaf(w1, b2f(v1.x), ax); ay = fmaf(w1, b2f(v1.y), ay);
        ax = fmaf(w2, b2f(v2.x), ax); ay = fmaf(w2, b2f(v2.y), ay);
        ax = fmaf(w3, b2f(v3.x), ax); ay = fmaf(w3, b2f(v3.y), ay);
    }
    for (; e < e1; ++e) {
        int s = csr_src[e];
        float ww = di * dinv[s];
        ushort2 v = h[(long)s * 64 + c2];
        ax = fmaf(ww, b2f(v.x), ax);
        ay = fmaf(ww, b2f(v.y), ay);
    }
    ushort2 o;
    o.x = f2b(fmaxf(ax, 0.f));
    o.y = f2b(fmaxf(ay, 0.f));
    out[(long)i * 64 + c2] = o;
}

// ---------------- graph segment boundaries (x_batch is sorted) ----------------

__global__ void graph_bounds(const int* __restrict__ batch, int* __restrict__ gstart,
                             int n, int ngraph) {
    int i = blockIdx.x * 256 + threadIdx.x;
    if (i >= n) return;
    int b = batch[i];
    int prev = (i == 0) ? -1 : batch[i - 1];
    for (int g = prev + 1; g <= b; ++g) gstart[g] = i;
    if (i == n - 1) {
        for (int g = b + 1; g <= ngraph; ++g) gstart[g] = n;
    }
}

// ---------------- pool + head GEMM + log_softmax ----------------

__global__ __launch_bounds__(256) void pool_head(const unsigned short* __restrict__ h2,
                                                 const int* __restrict__ gstart,
                                                 const float* __restrict__ Wh,
                                                 const float* __restrict__ bh,
                                                 float* __restrict__ out) {
    __shared__ float pl[2][DIM];
    int g = blockIdx.x;
    int c = threadIdx.x & 127;
    int s = threadIdx.x >> 7;   // 0/1 row-stream
    int i0 = gstart[g], i1 = gstart[g + 1];
    float p = 0.f;
    for (int i = i0 + s; i < i1; i += 2) p += b2f(h2[(long)i * DIM + c]);
    pl[s][c] = p;
    __syncthreads();
    if (threadIdx.x < NCLS) {
        int o = threadIdx.x;
        float logit = bh[o];
        #pragma unroll 8
        for (int cc = 0; cc < DIM; ++cc)
            logit = fmaf(pl[0][cc] + pl[1][cc], Wh[cc * NCLS + o], logit);
        float m = logit;
        #pragma unroll
        for (int d = 32; d >= 1; d >>= 1) m = fmaxf(m, __shfl_xor(m, d, 64));
        float ex = __expf(logit - m);
        float ssum = ex;
        #pragma unroll
        for (int d = 32; d >= 1; d >>= 1) ssum += __shfl_xor(ssum, d, 64);
        out[g * NCLS + o] = logit - m - __logf(ssum);
    }
}

// ---------------- launch ----------------

extern "C" void kernel_launch(void* const* d_in, const int* in_sizes, int n_in,
                              void* d_out, int out_size, void* d_ws, size_t ws_size,
                              hipStream_t stream) {
    const float* x  = (const float*)d_in[0];
    const int*   ei = (const int*)d_in[1];
    const int*   xb = (const int*)d_in[2];
    const float* W1 = (const float*)d_in[3];
    const float* b1 = (const float*)d_in[4];
    const float* W2 = (const float*)d_in[5];
    const float* b2 = (const float*)d_in[6];
    const float* Wh = (const float*)d_in[7];
    const float* bh = (const float*)d_in[8];
    float* out = (float*)d_out;

    const int N = in_sizes[0] / DIM;       // 50000
    const int E = in_sizes[1] / 2;         // 640000
    const int G = out_size / NCLS;         // 512
    const int* srcv = ei;
    const int* dstv = ei + E;

    // workspace carve-up
    char* w = (char*)d_ws;
    auto alloc = [&](size_t bytes) {
        char* p = w;
        w += (bytes + 255) & ~(size_t)255;
        return p;
    };
    int*   cnt     = (int*)alloc((size_t)N * 4);
    int*   cursor  = (int*)alloc((size_t)N * 4);
    int*   partial = (int*)alloc((size_t)N * 4);
    int*   bsum    = (int*)alloc(256 * 4);
    int*   row_off = (int*)alloc(((size_t)N + 1) * 4);
    int*   gstart  = (int*)alloc(((size_t)G + 1) * 4);
    int*   csr_src = (int*)alloc((size_t)E * 4);
    float* dinv    = (float*)alloc((size_t)N * 4);
    unsigned short* Htmp = (unsigned short*)alloc((size_t)N * DIM * 2);  // bf16
    unsigned short* H1   = (unsigned short*)alloc((size_t)N * DIM * 2);  // bf16

    hipMemsetAsync(cnt, 0, (size_t)N * 4, stream);

    const int eb = (E + 255) / 256;
    const int nb1024 = (N + 1023) / 1024;
    const int nb256 = (N + 255) / 256;

    count_dst<<<eb, 256, 0, stream>>>(dstv, cnt, E);
    scan_block<<<nb1024, 1024, 0, stream>>>(cnt, partial, bsum, dinv, N);
    scan_small<<<1, 64, 0, stream>>>(bsum, nb1024);
    finalize_rowoff<<<nb256, 256, 0, stream>>>(partial, bsum, row_off, cursor, N, E);
    scatter_csr<<<eb, 256, 0, stream>>>(srcv, dstv, cursor, csr_src, E);

    const int gb = (N + GTM - 1) / GTM;
    // layer 1
    gemm_xw<float><<<gb, 256, 0, stream>>>(x, W1, Htmp, N);
    aggregate<<<N, 64, 0, stream>>>((const ushort2*)Htmp, dinv, row_off, csr_src, b1,
                                    (ushort2*)H1, N);
    // layer 2
    gemm_xw<unsigned short><<<gb, 256, 0, stream>>>(H1, W2, Htmp, N);
    aggregate<<<N, 64, 0, stream>>>((const ushort2*)Htmp, dinv, row_off, csr_src, b2,
                                    (ushort2*)H1, N);
    // pool + head
    graph_bounds<<<nb256, 256, 0, stream>>>(xb, gstart, N, G);
    pool_head<<<G, 256, 0, stream>>>(H1, gstart, Wh, bh, out);
}

// Round 3
// 275.343 us; speedup vs baseline: 1.3085x; 1.0968x over previous
//
#include <hip/hip_runtime.h>
#include <hip/hip_bf16.h>

// GCN: h1 = relu(GCNConv(x, W1, b1)); h2 = relu(GCNConv(h1, W2, b2));
// pooled = segment_sum(h2, batch); out = log_softmax(pooled @ Wh + bh)
// Intermediates h stored bf16; GEMMs via mfma_f32_16x16x32_bf16 with
// W pre-swizzled into B-operand fragment layout (no LDS in the GEMM).

#define DIM 128
#define NCLS 64

typedef __attribute__((ext_vector_type(8))) short bf16x8;
typedef __attribute__((ext_vector_type(4))) float floatx4;

__device__ inline float b2f(unsigned short u) {
    union { unsigned int i; float f; } v; v.i = ((unsigned int)u) << 16; return v.f;
}
__device__ inline unsigned short f2b(float f) {
    union { float f; unsigned int i; } v; v.f = f;
    unsigned int r = v.i + 0x7FFFu + ((v.i >> 16) & 1u);  // round-to-nearest-even
    return (unsigned short)(r >> 16);
}

// ---------------- CSR build ----------------

__global__ void count_dst(const int* __restrict__ dst, int* __restrict__ cnt, int E) {
    int e = (blockIdx.x * 256 + threadIdx.x) * 4;
    if (e + 4 <= E) {
        int4 d = *(const int4*)(dst + e);
        atomicAdd(&cnt[d.x], 1); atomicAdd(&cnt[d.y], 1);
        atomicAdd(&cnt[d.z], 1); atomicAdd(&cnt[d.w], 1);
    } else {
        for (; e < E; ++e) atomicAdd(&cnt[dst[e]], 1);
    }
}

// per-1024 chunk exclusive scan (partial) + block sums + dinv
__global__ __launch_bounds__(1024) void scan_block(const int* __restrict__ cnt,
                                                   int* __restrict__ partial,
                                                   int* __restrict__ bsum,
                                                   float* __restrict__ dinv, int n) {
    __shared__ int wsum[16];
    int gid = blockIdx.x * 1024 + threadIdx.x;
    int v = (gid < n) ? cnt[gid] : 0;
    if (gid < n) dinv[gid] = rsqrtf(1.0f + (float)v);
    int lane = threadIdx.x & 63;
    int wave = threadIdx.x >> 6;
    int s = v;
    #pragma unroll
    for (int d = 1; d < 64; d <<= 1) {
        int t = __shfl_up(s, d, 64);
        if (lane >= d) s += t;
    }
    if (lane == 63) wsum[wave] = s;
    __syncthreads();
    if (threadIdx.x < 16) {
        int t = wsum[threadIdx.x];
        #pragma unroll
        for (int d = 1; d < 16; d <<= 1) {
            int u = __shfl_up(t, d, 64);
            if ((int)threadIdx.x >= d) t += u;
        }
        wsum[threadIdx.x] = t;  // inclusive over waves
    }
    __syncthreads();
    int woff = (wave == 0) ? 0 : wsum[wave - 1];
    if (gid < n) partial[gid] = woff + s - v;  // exclusive within chunk
    if (threadIdx.x == 0) bsum[blockIdx.x] = wsum[15];
}

__global__ void scan_small(int* __restrict__ bsum, int nb) {
    int l = threadIdx.x;
    int v = (l < nb) ? bsum[l] : 0;
    int s = v;
    #pragma unroll
    for (int d = 1; d < 64; d <<= 1) {
        int t = __shfl_up(s, d, 64);
        if (l >= d) s += t;
    }
    if (l < nb) bsum[l] = s - v;  // exclusive
}

__global__ void finalize_rowoff(const int* __restrict__ partial, const int* __restrict__ bsum,
                                int* __restrict__ row_off, int* __restrict__ cursor,
                                int n, int E) {
    int i = blockIdx.x * 256 + threadIdx.x;
    if (i < n) {
        int r = partial[i] + bsum[i >> 10];
        row_off[i] = r;
        cursor[i] = r;
    }
    if (i == 0) row_off[n] = E;
}

__global__ void scatter_csr(const int* __restrict__ src, const int* __restrict__ dst,
                            int* __restrict__ cursor, int* __restrict__ csr_src, int E) {
    int e = (blockIdx.x * 256 + threadIdx.x) * 4;
    if (e + 4 <= E) {
        int4 s = *(const int4*)(src + e);
        int4 d = *(const int4*)(dst + e);
        csr_src[atomicAdd(&cursor[d.x], 1)] = s.x;
        csr_src[atomicAdd(&cursor[d.y], 1)] = s.y;
        csr_src[atomicAdd(&cursor[d.z], 1)] = s.z;
        csr_src[atomicAdd(&cursor[d.w], 1)] = s.w;
    } else {
        for (; e < E; ++e) {
            int d = dst[e];
            csr_src[atomicAdd(&cursor[d], 1)] = src[e];
        }
    }
}

// ---------------- W pre-swizzle into B-operand fragment layout ----------------
// b_frag for (ntile, k0i): lane holds W[k0i*32 + quad*8 + j][ntile*16 + (lane&15)],
// quad = lane>>4, j = 0..7, stored contiguous: Wswz[((ntile*4+k0i)*64 + lane)*8 + j]

__global__ void prep_w(const float* __restrict__ W1, const float* __restrict__ W2,
                       unsigned short* __restrict__ O1, unsigned short* __restrict__ O2) {
    const float* W = blockIdx.x ? W2 : W1;
    unsigned short* O = blockIdx.x ? O2 : O1;
    for (int idx = threadIdx.x; idx < DIM * DIM; idx += 256) {
        int k = idx >> 7, nn = idx & 127;
        int ntile = nn >> 4, k0i = k >> 5;
        int lane = ((k >> 3) & 3) * 16 + (nn & 15);
        int j = k & 7;
        O[(((ntile * 4 + k0i) * 64) + lane) * 8 + j] = f2b(W[idx]);
    }
}

// ---------------- MFMA GEMM: C[N][128](bf16) = A[N][128] @ W ----------------
// 256 threads = 4 waves; wave handles 16 rows x 128 cols (8 ntiles x 4 k-steps).

template <typename T>
__global__ __launch_bounds__(256) void gemm_mfma(const T* __restrict__ A,
                                                 const unsigned short* __restrict__ Wswz,
                                                 unsigned short* __restrict__ C, int N) {
    const int wave = threadIdx.x >> 6;
    const int lane = threadIdx.x & 63;
    const int quad = lane >> 4;
    const int l16 = lane & 15;
    const int row0 = blockIdx.x * 64 + wave * 16;
    const int r = row0 + l16;           // A-operand row for this lane
    const int rc = (r < N) ? r : (N - 1);

    // load 4 A-fragments: a[k0i][j] = A[r][k0i*32 + quad*8 + j]
    bf16x8 a[4];
    #pragma unroll
    for (int k0i = 0; k0i < 4; ++k0i) {
        int k = k0i * 32 + quad * 8;
        if constexpr (__is_same(T, float)) {
            const float4* p = (const float4*)(A + (long)rc * DIM + k);
            float4 f0 = p[0], f1 = p[1];
            bf16x8 t;
            t[0] = (short)f2b(f0.x); t[1] = (short)f2b(f0.y);
            t[2] = (short)f2b(f0.z); t[3] = (short)f2b(f0.w);
            t[4] = (short)f2b(f1.x); t[5] = (short)f2b(f1.y);
            t[6] = (short)f2b(f1.z); t[7] = (short)f2b(f1.w);
            a[k0i] = t;
        } else {
            a[k0i] = *(const bf16x8*)(A + (long)rc * DIM + k);
        }
    }

    #pragma unroll
    for (int ntile = 0; ntile < 8; ++ntile) {
        floatx4 acc = {0.f, 0.f, 0.f, 0.f};
        #pragma unroll
        for (int k0i = 0; k0i < 4; ++k0i) {
            bf16x8 b = *(const bf16x8*)(Wswz + (((ntile * 4 + k0i) * 64) + lane) * 8);
            acc = __builtin_amdgcn_mfma_f32_16x16x32_bf16(a[k0i], b, acc, 0, 0, 0);
        }
        // C/D layout: col = lane&15, row = quad*4 + reg
        #pragma unroll
        for (int reg = 0; reg < 4; ++reg) {
            int rr = row0 + quad * 4 + reg;
            if (rr < N) C[(long)rr * DIM + ntile * 16 + l16] = f2b(acc[reg]);
        }
    }
}

// ---------------- neighbor aggregation + self loop + bias + relu (bf16 h) ----------------
// 4 waves per block, one node per wave; each lane handles a bf16 pair.

__global__ __launch_bounds__(256) void aggregate(const ushort2* __restrict__ h,
                                                 const float* __restrict__ dinv,
                                                 const int* __restrict__ row_off,
                                                 const int* __restrict__ csr_src,
                                                 const float* __restrict__ bias,
                                                 ushort2* __restrict__ out, int n) {
    int i = blockIdx.x * 4 + (threadIdx.x >> 6);
    if (i >= n) return;
    int c2 = threadIdx.x & 63;     // pair index 0..63
    float di = dinv[i];
    ushort2 hv = h[(long)i * 64 + c2];
    float ax = bias[2 * c2]     + di * di * b2f(hv.x);
    float ay = bias[2 * c2 + 1] + di * di * b2f(hv.y);
    int e0 = row_off[i], e1 = row_off[i + 1];
    int e = e0;
    for (; e + 4 <= e1; e += 4) {
        int s0 = csr_src[e], s1 = csr_src[e + 1], s2 = csr_src[e + 2], s3 = csr_src[e + 3];
        float w0 = di * dinv[s0], w1 = di * dinv[s1], w2 = di * dinv[s2], w3 = di * dinv[s3];
        ushort2 v0 = h[(long)s0 * 64 + c2];
        ushort2 v1 = h[(long)s1 * 64 + c2];
        ushort2 v2 = h[(long)s2 * 64 + c2];
        ushort2 v3 = h[(long)s3 * 64 + c2];
        ax = fmaf(w0, b2f(v0.x), ax); ay = fmaf(w0, b2f(v0.y), ay);
        ax = fmaf(w1, b2f(v1.x), ax); ay = fmaf(w1, b2f(v1.y), ay);
        ax = fmaf(w2, b2f(v2.x), ax); ay = fmaf(w2, b2f(v2.y), ay);
        ax = fmaf(w3, b2f(v3.x), ax); ay = fmaf(w3, b2f(v3.y), ay);
    }
    for (; e < e1; ++e) {
        int s = csr_src[e];
        float ww = di * dinv[s];
        ushort2 v = h[(long)s * 64 + c2];
        ax = fmaf(ww, b2f(v.x), ax);
        ay = fmaf(ww, b2f(v.y), ay);
    }
    ushort2 o;
    o.x = f2b(fmaxf(ax, 0.f));
    o.y = f2b(fmaxf(ay, 0.f));
    out[(long)i * 64 + c2] = o;
}

// ---------------- graph segment boundaries (x_batch is sorted) ----------------

__global__ void graph_bounds(const int* __restrict__ batch, int* __restrict__ gstart,
                             int n, int ngraph) {
    int i = blockIdx.x * 256 + threadIdx.x;
    if (i >= n) return;
    int b = batch[i];
    int prev = (i == 0) ? -1 : batch[i - 1];
    for (int g = prev + 1; g <= b; ++g) gstart[g] = i;
    if (i == n - 1) {
        for (int g = b + 1; g <= ngraph; ++g) gstart[g] = n;
    }
}

// ---------------- pool + head GEMM + log_softmax ----------------

__global__ __launch_bounds__(256) void pool_head(const unsigned short* __restrict__ h2,
                                                 const int* __restrict__ gstart,
                                                 const float* __restrict__ Wh,
                                                 const float* __restrict__ bh,
                                                 float* __restrict__ out) {
    __shared__ float pl[2][DIM];
    int g = blockIdx.x;
    int c = threadIdx.x & 127;
    int s = threadIdx.x >> 7;   // 0/1 row-stream
    int i0 = gstart[g], i1 = gstart[g + 1];
    float p = 0.f;
    for (int i = i0 + s; i < i1; i += 2) p += b2f(h2[(long)i * DIM + c]);
    pl[s][c] = p;
    __syncthreads();
    if (threadIdx.x < NCLS) {
        int o = threadIdx.x;
        float logit = bh[o];
        #pragma unroll 8
        for (int cc = 0; cc < DIM; ++cc)
            logit = fmaf(pl[0][cc] + pl[1][cc], Wh[cc * NCLS + o], logit);
        float m = logit;
        #pragma unroll
        for (int d = 32; d >= 1; d >>= 1) m = fmaxf(m, __shfl_xor(m, d, 64));
        float ex = __expf(logit - m);
        float ssum = ex;
        #pragma unroll
        for (int d = 32; d >= 1; d >>= 1) ssum += __shfl_xor(ssum, d, 64);
        out[g * NCLS + o] = logit - m - __logf(ssum);
    }
}

// ---------------- launch ----------------

extern "C" void kernel_launch(void* const* d_in, const int* in_sizes, int n_in,
                              void* d_out, int out_size, void* d_ws, size_t ws_size,
                              hipStream_t stream) {
    const float* x  = (const float*)d_in[0];
    const int*   ei = (const int*)d_in[1];
    const int*   xb = (const int*)d_in[2];
    const float* W1 = (const float*)d_in[3];
    const float* b1 = (const float*)d_in[4];
    const float* W2 = (const float*)d_in[5];
    const float* b2 = (const float*)d_in[6];
    const float* Wh = (const float*)d_in[7];
    const float* bh = (const float*)d_in[8];
    float* out = (float*)d_out;

    const int N = in_sizes[0] / DIM;       // 50000
    const int E = in_sizes[1] / 2;         // 640000
    const int G = out_size / NCLS;         // 512
    const int* srcv = ei;
    const int* dstv = ei + E;

    // workspace carve-up
    char* w = (char*)d_ws;
    auto alloc = [&](size_t bytes) {
        char* p = w;
        w += (bytes + 255) & ~(size_t)255;
        return p;
    };
    int*   cnt     = (int*)alloc((size_t)N * 4);
    int*   cursor  = (int*)alloc((size_t)N * 4);
    int*   partial = (int*)alloc((size_t)N * 4);
    int*   bsum    = (int*)alloc(256 * 4);
    int*   row_off = (int*)alloc(((size_t)N + 1) * 4);
    int*   gstart  = (int*)alloc(((size_t)G + 1) * 4);
    int*   csr_src = (int*)alloc((size_t)E * 4);
    float* dinv    = (float*)alloc((size_t)N * 4);
    unsigned short* Wswz1 = (unsigned short*)alloc((size_t)DIM * DIM * 2);
    unsigned short* Wswz2 = (unsigned short*)alloc((size_t)DIM * DIM * 2);
    unsigned short* Htmp  = (unsigned short*)alloc((size_t)N * DIM * 2);  // bf16
    unsigned short* H1    = (unsigned short*)alloc((size_t)N * DIM * 2);  // bf16

    hipMemsetAsync(cnt, 0, (size_t)N * 4, stream);

    const int eb4 = (E + 1023) / 1024;
    const int nb1024 = (N + 1023) / 1024;
    const int nb256 = (N + 255) / 256;

    prep_w<<<2, 256, 0, stream>>>(W1, W2, Wswz1, Wswz2);
    count_dst<<<eb4, 256, 0, stream>>>(dstv, cnt, E);
    scan_block<<<nb1024, 1024, 0, stream>>>(cnt, partial, bsum, dinv, N);
    scan_small<<<1, 64, 0, stream>>>(bsum, nb1024);
    finalize_rowoff<<<nb256, 256, 0, stream>>>(partial, bsum, row_off, cursor, N, E);
    scatter_csr<<<eb4, 256, 0, stream>>>(srcv, dstv, cursor, csr_src, E);

    const int gb = (N + 63) / 64;
    const int ab = (N + 3) / 4;
    // layer 1
    gemm_mfma<float><<<gb, 256, 0, stream>>>(x, Wswz1, Htmp, N);
    aggregate<<<ab, 256, 0, stream>>>((const ushort2*)Htmp, dinv, row_off, csr_src, b1,
                                      (ushort2*)H1, N);
    // layer 2
    gemm_mfma<unsigned short><<<gb, 256, 0, stream>>>(H1, Wswz2, Htmp, N);
    aggregate<<<ab, 256, 0, stream>>>((const ushort2*)Htmp, dinv, row_off, csr_src, b2,
                                      (ushort2*)H1, N);
    // pool + head
    graph_bounds<<<nb256, 256, 0, stream>>>(xb, gstart, N, G);
    pool_head<<<G, 256, 0, stream>>>(H1, gstart, Wh, bh, out);
}